// Round 4
// baseline (453.438 us; speedup 1.0000x reference)
//
#include <hip/hip_runtime.h>
#include <math.h>

// ACT skip-RNN, H=O=4096, I=4095 (xin=[flag,x], len 4096).
// R10: single fused persistent kernel (kills inter-kernel drain/flush/ramp).
//   k_prep : zero ws ctl words + stage aligned xin into out[H..2H)
//   k_main : 1024 blocks x 256 (4 blocks/CU co-resident, no LDS arrays);
//            phase A: wave = full row of W_ih+W_hh (step-0 matvec),
//                     s1 -> ws sb0, halt partial -> ws hpart;
//            grid barrier; per-block uniform halt decision (16KB reduce);
//            common: phase C = wave-per-row W_out matvec + epilogue;
//            rare: steps 1..15 inline (1 row/wave/step, hdot atomics + barrier).
// out scratch: [H..2H)=xin (dead before phase C overwrites with s output).
// ws float layout: [0]=cnt [1]=gen [16..32)=hdot[16]
//   [32..32+H)=sb0 [32+H..32+2H)=sb1 [32+2H..32+3H)=hpart  (~49 KB)

#define H      4096
#define NMAX   16
#define THRESH 0.99f         // 1.0 - EPS
#define RG     1024
#define RT     256

__device__ __forceinline__ float wave_reduce(float a) {
    #pragma unroll
    for (int off = 32; off > 0; off >>= 1) a += __shfl_down(a, off);
    return a;
}

__device__ __forceinline__ void grid_barrier(int* cnt, int* gen) {
    __syncthreads();
    if (threadIdx.x == 0) {
        __threadfence();
        int g = __hip_atomic_load(gen, __ATOMIC_RELAXED, __HIP_MEMORY_SCOPE_AGENT);
        int prev = __hip_atomic_fetch_add(cnt, 1, __ATOMIC_ACQ_REL, __HIP_MEMORY_SCOPE_AGENT);
        if (prev == RG - 1) {
            __hip_atomic_store(cnt, 0, __ATOMIC_RELAXED, __HIP_MEMORY_SCOPE_AGENT);
            __hip_atomic_fetch_add(gen, 1, __ATOMIC_RELEASE, __HIP_MEMORY_SCOPE_AGENT);
        } else {
            while (__hip_atomic_load(gen, __ATOMIC_ACQUIRE, __HIP_MEMORY_SCOPE_AGENT) == g)
                __builtin_amdgcn_s_sleep(8);
        }
        __threadfence();
    }
    __syncthreads();
}

// ---------------- k_prep: control-word zero + aligned xin staging ----------------
__global__ __launch_bounds__(256) void k_prep(
    const float* __restrict__ x, float* __restrict__ ws, float* __restrict__ out)
{
    const int i = blockIdx.x * 256 + threadIdx.x;
    if (i < 32) ws[i] = 0.f;               // cnt/gen/hdot
    if (i == 0) out[H] = 0.f;              // xin[0] flag slot (t==0 flag via W col 0)
    if (i < H - 1) out[H + 1 + i] = x[i];
}

// ---------------- k_main: fused step0 + halt + rare loop + output ----------------
__global__ __launch_bounds__(RT, 4) void k_main(
    const float* __restrict__ s0,    const float* __restrict__ y0,
    const float* __restrict__ h0,
    const float* __restrict__ W_ih,  const float* __restrict__ b_ih,
    const float* __restrict__ W_hh,  const float* __restrict__ b_hh,
    const float* __restrict__ W_halt,const float* __restrict__ b_halt,
    const float* __restrict__ W_out, const float* __restrict__ b_out,
    float* ws, float* __restrict__ out)
{
    const int tid  = threadIdx.x, bid = blockIdx.x;
    const float h0v = h0[0];

    // ---- uniform pass-through: binarize(h0)==1, ACT loop never runs ----
    if (h0v >= THRESH) {                   // no barriers on this path
        const int i = bid * RT + tid;
        if (i < H) { out[i] = y0[i]; out[H + i] = s0[i]; }
        if (i == 0) { out[2*H] = 0.f; out[2*H + 1] = h0v - 1.f; }
        return;
    }

    const int wave = tid >> 6, lane = tid & 63;
    const int row  = (bid << 2) + wave;    // 1024 blocks x 4 waves = 4096 rows

    float* sb0   = ws + 32;
    float* sb1   = ws + 32 + H;
    float* hpart = ws + 32 + 2 * H;
    float* hdot  = ws + 16;

    const float4* wi4 = (const float4*)(W_ih + (size_t)row * H);
    const float4* wh4 = (const float4*)(W_hh + (size_t)row * H);
    const float4* xv4 = (const float4*)(out + H);   // staged xin (flag slot = 0)
    const float4* sv4 = (const float4*)s0;

    // per-row scalars (L2-hot broadcast-ish loads)
    const float bi  = b_ih[row];
    const float bhh = b_hh[row];
    const float w0c = W_ih[(size_t)row * H];        // xin[0]=1 only at t==0
    const float whl = W_halt[row];
    const float bha = b_halt[0];

    // ---- phase A: step-0 matvec, wave = full row, 8-deep register batches ----
    {
        float a0 = 0.f, a1 = 0.f;
        float4 wreg[8];
        #pragma unroll
        for (int hseg = 0; hseg < 2; ++hseg) {
            const int off = hseg << 9;              // 0, 512 (float4 units)
            #pragma unroll
            for (int k = 0; k < 8; ++k) wreg[k] = wi4[off + lane + (k << 6)];
            #pragma unroll
            for (int k = 0; k < 8; ++k) {
                float4 v = xv4[off + lane + (k << 6)];
                a0 += wreg[k].x*v.x + wreg[k].y*v.y + wreg[k].z*v.z + wreg[k].w*v.w;
            }
            #pragma unroll
            for (int k = 0; k < 8; ++k) wreg[k] = wh4[off + lane + (k << 6)];
            #pragma unroll
            for (int k = 0; k < 8; ++k) {
                float4 v = sv4[off + lane + (k << 6)];
                a1 += wreg[k].x*v.x + wreg[k].y*v.y + wreg[k].z*v.z + wreg[k].w*v.w;
            }
        }
        float a = wave_reduce(a0 + a1);
        if (lane == 0) {
            float s1 = tanhf(a + bi + bhh + w0c);
            sb0[row]   = s1;
            hpart[row] = whl * s1;
        }
    }

    grid_barrier((int*)ws, (int*)ws + 1);

    // ---- per-block uniform step-0 halt decision (identical reduce everywhere) ----
    float acc;
    {
        const float4* p4 = (const float4*)hpart;
        float a = 0.f;
        #pragma unroll
        for (int j = 0; j < 4; ++j) {
            float4 v = p4[tid + (j << 8)];
            a += v.x + v.y + v.z + v.w;
        }
        a = wave_reduce(a);
        __shared__ float pr[4];
        if (lane == 0) pr[wave] = a;
        __syncthreads();
        float hd = pr[0] + pr[1] + pr[2] + pr[3];
        acc = h0v + 2.f / (1.f + expf(-(hd + bha)));
    }

    bool  halted;
    int   sel = 0, ponder = 0;
    float last_acc;

    if (acc >= THRESH) {                   // common: halt at step 0
        halted = true; last_acc = acc;
    } else {
        // ---- rare path: steps 1..15, 1 row/wave/step, uniform decisions ----
        halted = false; last_acc = 0.f; ponder = 1;
        for (int t = 1; t < NMAX; ++t) {
            const float* scur = (t & 1) ? sb0 : sb1;
            float*       snew = (t & 1) ? sb1 : sb0;
            const float4* sc4 = (const float4*)scur;

            float a0 = 0.f, a1 = 0.f;
            #pragma unroll 4
            for (int k = 0; k < 16; ++k) {
                const int idx = lane + (k << 6);
                float4 wa = wi4[idx], wb = wh4[idx];
                float4 va = xv4[idx], vb = sc4[idx];
                a0 += wa.x*va.x + wa.y*va.y + wa.z*va.z + wa.w*va.w;
                a1 += wb.x*vb.x + wb.y*vb.y + wb.z*vb.z + wb.w*vb.w;
            }
            float a = wave_reduce(a0 + a1);
            if (lane == 0) {
                float sv = tanhf(a + bi + bhh);    // no w0c: flag=0 for t>=1
                snew[row] = sv;
                atomicAdd(&hdot[t], whl * sv);     // rare: contention OK
            }

            grid_barrier((int*)ws, (int*)ws + 1);

            float hd = ((volatile float*)hdot)[t];
            acc += 2.f / (1.f + expf(-(hd + bha)));
            if (acc >= THRESH) {
                halted = true; last_acc = acc; sel = (t & 1) ? 1 : 0; break;
            }
            ponder++;
        }
    }

    // ---- phase C: output matvec + epilogue (no barrier needed: hpart in ws) ----
    if (halted) {
        const float* sfin = sel ? sb1 : sb0;
        const float4* wo4 = (const float4*)(W_out + (size_t)row * H);
        const float4* vf4 = (const float4*)sfin;
        const float bo = b_out[row];

        float a0 = 0.f, a1 = 0.f;
        float4 wreg[8];
        #pragma unroll
        for (int hseg = 0; hseg < 2; ++hseg) {
            const int off = hseg << 9;
            #pragma unroll
            for (int k = 0; k < 8; ++k) wreg[k] = wo4[off + lane + (k << 6)];
            #pragma unroll
            for (int k = 0; k < 8; ++k) {
                float4 v = vf4[off + lane + (k << 6)];
                a0 += wreg[k].x*v.x + wreg[k].y*v.y + wreg[k].z*v.z + wreg[k].w*v.w;
            }
        }
        float a = wave_reduce(a0 + a1);
        if (lane == 0) {
            out[row]     = a + bo;         // overwrites old scratch: safe
            out[H + row] = sfin[row];      // overwrites xin: all reads done
        }
    } else {                               // never halted within NMAX
        const int i = bid * RT + tid;
        if (i < H) { out[i] = 0.f; out[H + i] = 0.f; }
    }
    if (bid == 0 && tid == 0) {
        out[2*H]     = (float)ponder;
        out[2*H + 1] = halted ? (last_acc - 1.f) : -1.f;
    }
}

extern "C" void kernel_launch(void* const* d_in, const int* in_sizes, int n_in,
                              void* d_out, int out_size, void* d_ws, size_t ws_size,
                              hipStream_t stream) {
    const float* x      = (const float*)d_in[0];
    const float* s0     = (const float*)d_in[1];
    const float* y0     = (const float*)d_in[2];
    const float* h0     = (const float*)d_in[3];
    const float* W_ih   = (const float*)d_in[4];
    const float* b_ih   = (const float*)d_in[5];
    const float* W_hh   = (const float*)d_in[6];
    const float* b_hh   = (const float*)d_in[7];
    const float* W_halt = (const float*)d_in[8];
    const float* b_halt = (const float*)d_in[9];
    const float* W_out  = (const float*)d_in[10];
    const float* b_out  = (const float*)d_in[11];
    float* out = (float*)d_out;
    float* ws  = (float*)d_ws;   // (32 + 3*4096)*4 B ≈ 49 KB used

    k_prep<<<dim3(16),  dim3(256), 0, stream>>>(x, ws, out);
    k_main<<<dim3(RG),  dim3(RT),  0, stream>>>(
        s0, y0, h0, W_ih, b_ih, W_hh, b_hh, W_halt, b_halt, W_out, b_out, ws, out);
}

// Round 6
// 208.045 us; speedup vs baseline: 2.1795x; 2.1795x over previous
//
#include <hip/hip_runtime.h>
#include <math.h>

// ACT skip-RNN, H=O=4096, I=4095 (xin=[flag,x], len 4096).
// R11b: R11 with the nontemporal builtin fixed (needs native ext_vector type,
// not HIP_vector_type). Theory: nt weight loads bypass the L2-allocate/L3-hit
// path that caps the cached weight stream at ~2.5 TB/s aggregate.
//   k_prep  : zero ws ctl words + stage aligned xin into out[H..2H)
//   k_step0 : 1024 blocks x 256 (4 blocks/CU); wave = full row of W_ih+W_hh;
//             16-deep nt weight batches; vectors from L2; no LDS reduce.
//   k_rest  : unchanged — halt decision from partials; rare path persistent.
//   k_out   : 1024 blocks x 256; wave = full row of W_out (nt); s_halt from L2.
// out scratch: [0..H)=hpartials, [H..2H)=xin (both dead before k_out writes).
// ws float layout: [0]=cnt [1]=gen [4]=halted [5]=sel [6]=ponder [8]=last_acc
//   [16..32)=hdot[16] [32..32+H)=sb0 [32+H..32+2H)=sb1   (~33 KB)

#define H      4096
#define NMAX   16
#define THRESH 0.99f         // 1.0 - EPS

typedef float nf4 __attribute__((ext_vector_type(4)));   // native vec for nt loads

__device__ __forceinline__ float wave_reduce(float a) {
    #pragma unroll
    for (int off = 32; off > 0; off >>= 1) a += __shfl_down(a, off);
    return a;
}

// ---------------- k_prep: control-word zero + aligned xin staging ----------------
__global__ __launch_bounds__(256) void k_prep(
    const float* __restrict__ x, float* __restrict__ ws, float* __restrict__ out)
{
    const int i = blockIdx.x * 256 + threadIdx.x;
    if (i < 32) ws[i] = 0.f;               // cnt/gen/halted/sel/ponder/hdot
    if (i == 0) out[H] = 0.f;              // xin[0] flag slot (t==0 flag via W col 0)
    if (i < H - 1) out[H + 1 + i] = x[i];
}

// ---------------- k_step0: step-0 matvec ----------------
// 1024 blocks x 256 thr; wave w owns row bid*4+w entirely: 16 float4 of W_ih
// + 16 float4 of W_hh per lane, nontemporal (streaming, no L2 allocate).
// Vectors (xin, s0) re-read from L2 (proven free in R7). Lane0 writes results
// directly — no cross-wave reduce stage.
__global__ __launch_bounds__(256, 4) void k_step0(
    const float* __restrict__ s0,     const float* __restrict__ h0,
    const float* __restrict__ W_ih,   const float* __restrict__ b_ih,
    const float* __restrict__ W_hh,   const float* __restrict__ b_hh,
    const float* __restrict__ W_halt,
    float* __restrict__ ws, float* __restrict__ out)
{
    if (h0[0] >= THRESH) return;           // ACT loop never executes

    const int tid  = threadIdx.x, bid = blockIdx.x;
    const int wave = tid >> 6,   lane = tid & 63;
    const int row  = (bid << 2) + wave;    // 1024 x 4 = 4096 rows

    const nf4* wi4 = (const nf4*)(W_ih + (size_t)row * H);
    const nf4* wh4 = (const nf4*)(W_hh + (size_t)row * H);
    const float4* xv4 = (const float4*)(out + H);   // staged xin (L2-hot)
    const float4* sv4 = (const float4*)s0;          // L2-hot

    // ---- stream 1: W_ih full row, 16 nt loads in flight, consume vs xin
    nf4 wreg[16];
    #pragma unroll
    for (int k = 0; k < 16; ++k)
        wreg[k] = __builtin_nontemporal_load(&wi4[lane + (k << 6)]);
    float a0 = 0.f;
    #pragma unroll
    for (int k = 0; k < 16; ++k) {
        float4 v = xv4[lane + (k << 6)];
        a0 += wreg[k].x*v.x + wreg[k].y*v.y + wreg[k].z*v.z + wreg[k].w*v.w;
    }
    // ---- stream 2: W_hh full row, consume vs s0
    #pragma unroll
    for (int k = 0; k < 16; ++k)
        wreg[k] = __builtin_nontemporal_load(&wh4[lane + (k << 6)]);
    float a1 = 0.f;
    #pragma unroll
    for (int k = 0; k < 16; ++k) {
        float4 v = sv4[lane + (k << 6)];
        a1 += wreg[k].x*v.x + wreg[k].y*v.y + wreg[k].z*v.z + wreg[k].w*v.w;
    }

    float a = wave_reduce(a0 + a1);
    if (lane == 0) {
        float z = a + b_ih[row] + b_hh[row] + W_ih[(size_t)row * H];  // xin[0]=1
        float s1 = tanhf(z);
        ws[32 + row] = s1;                 // sb0 = s1
        out[row] = W_halt[row] * s1;       // private halt partial
    }
}

// ---------------- k_rest: halt decision + rare path (steps 1..15) ----------------
#define RG   256
#define RT   256

__device__ __forceinline__ void grid_barrier(int* cnt, int* gen) {
    __syncthreads();
    if (threadIdx.x == 0) {
        __threadfence();
        int g = __hip_atomic_load(gen, __ATOMIC_RELAXED, __HIP_MEMORY_SCOPE_AGENT);
        int prev = __hip_atomic_fetch_add(cnt, 1, __ATOMIC_ACQ_REL, __HIP_MEMORY_SCOPE_AGENT);
        if (prev == RG - 1) {
            __hip_atomic_store(cnt, 0, __ATOMIC_RELAXED, __HIP_MEMORY_SCOPE_AGENT);
            __hip_atomic_fetch_add(gen, 1, __ATOMIC_RELEASE, __HIP_MEMORY_SCOPE_AGENT);
        } else {
            while (__hip_atomic_load(gen, __ATOMIC_ACQUIRE, __HIP_MEMORY_SCOPE_AGENT) == g)
                __builtin_amdgcn_s_sleep(8);
        }
        __threadfence();
    }
    __syncthreads();
}

__global__ __launch_bounds__(RT) void k_rest(
    const float* __restrict__ x,
    const float* __restrict__ h0,
    const float* __restrict__ W_ih,   const float* __restrict__ b_ih,
    const float* __restrict__ W_hh,   const float* __restrict__ b_hh,
    const float* __restrict__ W_halt, const float* __restrict__ b_halt,
    const float* __restrict__ hpart,  float* ws)
{
    int* wsI = (int*)ws;
    if (h0[0] >= THRESH) return;     // no steps ran at all

    const int tid = threadIdx.x, bid = blockIdx.x;
    const int wave = tid >> 6, lane = tid & 63;

    // ---- recompute step-0 halt decision from partials (uniform across blocks)
    {
        const float4* p4 = (const float4*)hpart;   // out[0..H) as H/4 float4
        float a = 0.f;
        #pragma unroll
        for (int j = 0; j < 4; ++j) {
            float4 v = p4[tid + (j << 8)];
            a += v.x + v.y + v.z + v.w;
        }
        a = wave_reduce(a);
        __shared__ float pr[4];
        if (lane == 0) pr[wave] = a;
        __syncthreads();
        float hd  = pr[0] + pr[1] + pr[2] + pr[3];
        float sg  = 1.f / (1.f + expf(-(hd + b_halt[0])));
        float acc0 = h0[0] + 2.f * sg;
        if (acc0 >= THRESH) {        // halted at step 0: common case
            if (bid == 0 && tid == 0) {
                wsI[4] = 1; wsI[5] = 0; wsI[6] = 0; ws[8] = acc0;
            }
            return;
        }
        if (bid == 0 && tid == 0) { wsI[4] = 0; }
        __syncthreads();
    }

    float* hdot = ws + 16;
    float* sb0  = ws + 32;
    float* sb1  = ws + 32 + H;

    __shared__ float xl[H];
    __shared__ float sl[H];
    if (tid == 0) xl[0] = 0.f;       // flag = 0 for all t >= 1
    for (int i = tid; i < H - 1; i += RT) xl[i + 1] = x[i];

    // recompute acc0 locally (cheap, uniform)
    float acc;
    {
        const float4* p4 = (const float4*)hpart;
        float a = 0.f;
        #pragma unroll
        for (int j = 0; j < 4; ++j) {
            float4 v = p4[tid + (j << 8)];
            a += v.x + v.y + v.z + v.w;
        }
        a = wave_reduce(a);
        __shared__ float pr2[4];
        if (lane == 0) pr2[wave] = a;
        __syncthreads();
        float hd = pr2[0] + pr2[1] + pr2[2] + pr2[3];
        acc = h0[0] + 2.f / (1.f + expf(-(hd + b_halt[0])));
    }
    int   ponder = 1;
    const float bh = b_halt[0];
    bool  halted = false;
    int   sel = 0;
    float last_acc = 0.f;

    for (int t = 1; t < NMAX; ++t) {
        const float* scur = (t & 1) ? sb0 : sb1;
        float*       snew = (t & 1) ? sb1 : sb0;

        __syncthreads();
        for (int i = tid; i < H / 4; i += RT)
            ((float4*)sl)[i] = ((const float4*)scur)[i];
        __syncthreads();

        for (int r = 0; r < 4; ++r) {
            const int row = bid * 16 + r * 4 + wave;
            const float4* wih = (const float4*)(W_ih + (size_t)row * H);
            const float4* whh = (const float4*)(W_hh + (size_t)row * H);
            float a0 = 0.f, a1 = 0.f;
            #pragma unroll 4
            for (int k = 0; k < 16; ++k) {
                const int idx = lane + (k << 6);
                float4 wa = wih[idx], wb = whh[idx];
                float4 va = ((const float4*)xl)[idx], vb = ((const float4*)sl)[idx];
                a0 += wa.x*va.x + wa.y*va.y + wa.z*va.z + wa.w*va.w;
                a1 += wb.x*vb.x + wb.y*vb.y + wb.z*vb.z + wb.w*vb.w;
            }
            float a = wave_reduce(a0 + a1);
            if (lane == 0) {
                float sv = tanhf(a + b_ih[row] + b_hh[row]);
                snew[row] = sv;
                atomicAdd(&hdot[t], W_halt[row] * sv);   // rare path: contention OK
            }
        }

        grid_barrier((int*)ws, (int*)ws + 1);

        float hd = ((volatile float*)hdot)[t];
        float sg = 1.f / (1.f + expf(-(hd + bh)));
        acc += 2.f * sg;
        if (acc >= THRESH) { halted = true; last_acc = acc; sel = (t & 1) ? 1 : 0; break; }
        ponder++;
    }

    if (bid == 0 && tid == 0) {
        wsI[4] = halted ? 1 : 0;
        wsI[5] = sel;
        wsI[6] = ponder;
        ws[8]  = last_acc;
    }
}

// ---------------- k_out: output matvec + epilogue ----------------
// 1024 blocks x 256 thr; wave = full row of W_out (nt); s_halt read from L2.
__global__ __launch_bounds__(256, 4) void k_out(
    const float* __restrict__ s0,    const float* __restrict__ y0,
    const float* __restrict__ h0,
    const float* __restrict__ W_out, const float* __restrict__ b_out,
    const float* __restrict__ ws, float* __restrict__ out)
{
    const float h0v = h0[0];
    const int tid = threadIdx.x, bid = blockIdx.x;

    if (h0v >= THRESH) {             // binarize(h0)==1: pass-through
        const int i = bid * 256 + tid;
        if (i < H) { out[i] = y0[i]; out[H + i] = s0[i]; }
        if (i == 0) { out[2*H] = 0.f; out[2*H + 1] = h0v - 1.f; }
        return;
    }

    const int* wsI = (const int*)ws;
    if (!wsI[4]) {                   // never halted within NMAX steps
        const int i = bid * 256 + tid;
        if (i < H) { out[i] = 0.f; out[H + i] = 0.f; }
        if (i == 0) { out[2*H] = (float)wsI[6]; out[2*H + 1] = -1.f; }
        return;
    }

    const float* sfin = ws + 32 + (wsI[5] ? H : 0);
    const int wave = tid >> 6, lane = tid & 63;
    const int row  = (bid << 2) + wave;

    const nf4* w4 = (const nf4*)(W_out + (size_t)row * H);
    const float4* v4 = (const float4*)sfin;

    nf4 wreg[16];
    #pragma unroll
    for (int k = 0; k < 16; ++k)
        wreg[k] = __builtin_nontemporal_load(&w4[lane + (k << 6)]);
    float a0 = 0.f;
    #pragma unroll
    for (int k = 0; k < 16; ++k) {
        float4 v = v4[lane + (k << 6)];
        a0 += wreg[k].x*v.x + wreg[k].y*v.y + wreg[k].z*v.z + wreg[k].w*v.w;
    }

    float a = wave_reduce(a0);
    if (lane == 0) {
        out[row]     = a + b_out[row];
        out[H + row] = sfin[row];
        if (bid == 0 && wave == 0) {
            out[2*H]     = (float)wsI[6];
            out[2*H + 1] = ws[8] - 1.f;
        }
    }
}

extern "C" void kernel_launch(void* const* d_in, const int* in_sizes, int n_in,
                              void* d_out, int out_size, void* d_ws, size_t ws_size,
                              hipStream_t stream) {
    const float* x      = (const float*)d_in[0];
    const float* s0     = (const float*)d_in[1];
    const float* y0     = (const float*)d_in[2];
    const float* h0     = (const float*)d_in[3];
    const float* W_ih   = (const float*)d_in[4];
    const float* b_ih   = (const float*)d_in[5];
    const float* W_hh   = (const float*)d_in[6];
    const float* b_hh   = (const float*)d_in[7];
    const float* W_halt = (const float*)d_in[8];
    const float* b_halt = (const float*)d_in[9];
    const float* W_out  = (const float*)d_in[10];
    const float* b_out  = (const float*)d_in[11];
    float* out = (float*)d_out;
    float* ws  = (float*)d_ws;   // (32 + 2*4096)*4 B ≈ 33 KB used

    k_prep<<<dim3(16),   dim3(256), 0, stream>>>(x, ws, out);
    k_step0<<<dim3(1024), dim3(256), 0, stream>>>(
        s0, h0, W_ih, b_ih, W_hh, b_hh, W_halt, ws, out);
    k_rest<<<dim3(RG),   dim3(RT),  0, stream>>>(
        x, h0, W_ih, b_ih, W_hh, b_hh, W_halt, b_halt, out, ws);
    k_out<<<dim3(1024),  dim3(256), 0, stream>>>(
        s0, y0, h0, W_out, b_out, ws, out);
}

// Round 7
// 206.813 us; speedup vs baseline: 2.1925x; 1.0060x over previous
//
#include <hip/hip_runtime.h>
#include <math.h>

// ACT skip-RNN, H=O=4096, I=4095 (xin=[flag,x], len 4096).
// R12: ping-pong nt weight batches (never drain the vmem queue to 0).
//   k_prep  : zero ws ctl words + stage aligned xin into out[H..2H)
//   k_step0 : 1024 blocks x 256 (4 blocks/CU); wave = full row; dual 8-deep
//             nt batches A/B: consume A while B in flight, reload behind.
//   k_rest  : unchanged — halt decision from partials; rare path persistent.
//   k_out   : 512 blocks x 256; wave = 2 rows (rowA, rowA+2048) of W_out,
//             same ping-pong; s_halt from L2.
// out scratch: [0..H)=hpartials, [H..2H)=xin (both dead before k_out writes).
// ws float layout: [0]=cnt [1]=gen [4]=halted [5]=sel [6]=ponder [8]=last_acc
//   [16..32)=hdot[16] [32..32+H)=sb0 [32+H..32+2H)=sb1   (~33 KB)

#define H      4096
#define NMAX   16
#define THRESH 0.99f         // 1.0 - EPS

typedef float nf4 __attribute__((ext_vector_type(4)));   // native vec for nt loads

__device__ __forceinline__ float wave_reduce(float a) {
    #pragma unroll
    for (int off = 32; off > 0; off >>= 1) a += __shfl_down(a, off);
    return a;
}

// ---------------- k_prep: control-word zero + aligned xin staging ----------------
__global__ __launch_bounds__(256) void k_prep(
    const float* __restrict__ x, float* __restrict__ ws, float* __restrict__ out)
{
    const int i = blockIdx.x * 256 + threadIdx.x;
    if (i < 32) ws[i] = 0.f;               // cnt/gen/halted/sel/ponder/hdot
    if (i == 0) out[H] = 0.f;              // xin[0] flag slot (t==0 flag via W col 0)
    if (i < H - 1) out[H + 1 + i] = x[i];
}

// ---------------- k_step0: step-0 matvec ----------------
// 1024 blocks x 256 thr; wave w owns row bid*4+w. Dual 8-deep nt batches:
// in-flight never drops below ~8 float4/wave (vs 16->0 bursts in R11b).
__global__ __launch_bounds__(256, 4) void k_step0(
    const float* __restrict__ s0,     const float* __restrict__ h0,
    const float* __restrict__ W_ih,   const float* __restrict__ b_ih,
    const float* __restrict__ W_hh,   const float* __restrict__ b_hh,
    const float* __restrict__ W_halt,
    float* __restrict__ ws, float* __restrict__ out)
{
    if (h0[0] >= THRESH) return;           // ACT loop never executes

    const int tid  = threadIdx.x, bid = blockIdx.x;
    const int wave = tid >> 6,   lane = tid & 63;
    const int row  = (bid << 2) + wave;    // 1024 x 4 = 4096 rows

    const nf4* wi4 = (const nf4*)(W_ih + (size_t)row * H);
    const nf4* wh4 = (const nf4*)(W_hh + (size_t)row * H);
    const float4* xv4 = (const float4*)(out + H);   // staged xin (L2-hot)
    const float4* sv4 = (const float4*)s0;          // L2-hot

    nf4 A[8], B[8];
    #pragma unroll
    for (int k = 0; k < 8; ++k)
        A[k] = __builtin_nontemporal_load(&wi4[lane + (k << 6)]);
    #pragma unroll
    for (int k = 0; k < 8; ++k)
        B[k] = __builtin_nontemporal_load(&wi4[lane + ((k + 8) << 6)]);

    float a0 = 0.f, a1 = 0.f;
    // consume A (wi lo) vs xin lo, then refill A with wh lo (B still in flight)
    #pragma unroll
    for (int k = 0; k < 8; ++k) {
        float4 v = xv4[lane + (k << 6)];
        a0 += A[k].x*v.x + A[k].y*v.y + A[k].z*v.z + A[k].w*v.w;
    }
    #pragma unroll
    for (int k = 0; k < 8; ++k)
        A[k] = __builtin_nontemporal_load(&wh4[lane + (k << 6)]);
    // consume B (wi hi) vs xin hi, then refill B with wh hi (A in flight)
    #pragma unroll
    for (int k = 0; k < 8; ++k) {
        float4 v = xv4[lane + ((k + 8) << 6)];
        a0 += B[k].x*v.x + B[k].y*v.y + B[k].z*v.z + B[k].w*v.w;
    }
    #pragma unroll
    for (int k = 0; k < 8; ++k)
        B[k] = __builtin_nontemporal_load(&wh4[lane + ((k + 8) << 6)]);
    // consume A (wh lo) vs s0 lo
    #pragma unroll
    for (int k = 0; k < 8; ++k) {
        float4 v = sv4[lane + (k << 6)];
        a1 += A[k].x*v.x + A[k].y*v.y + A[k].z*v.z + A[k].w*v.w;
    }
    // consume B (wh hi) vs s0 hi
    #pragma unroll
    for (int k = 0; k < 8; ++k) {
        float4 v = sv4[lane + ((k + 8) << 6)];
        a1 += B[k].x*v.x + B[k].y*v.y + B[k].z*v.z + B[k].w*v.w;
    }

    float a = wave_reduce(a0 + a1);
    if (lane == 0) {
        float z = a + b_ih[row] + b_hh[row] + W_ih[(size_t)row * H];  // xin[0]=1
        float s1 = tanhf(z);
        ws[32 + row] = s1;                 // sb0 = s1
        out[row] = W_halt[row] * s1;       // private halt partial
    }
}

// ---------------- k_rest: halt decision + rare path (steps 1..15) ----------------
#define RG   256
#define RT   256

__device__ __forceinline__ void grid_barrier(int* cnt, int* gen) {
    __syncthreads();
    if (threadIdx.x == 0) {
        __threadfence();
        int g = __hip_atomic_load(gen, __ATOMIC_RELAXED, __HIP_MEMORY_SCOPE_AGENT);
        int prev = __hip_atomic_fetch_add(cnt, 1, __ATOMIC_ACQ_REL, __HIP_MEMORY_SCOPE_AGENT);
        if (prev == RG - 1) {
            __hip_atomic_store(cnt, 0, __ATOMIC_RELAXED, __HIP_MEMORY_SCOPE_AGENT);
            __hip_atomic_fetch_add(gen, 1, __ATOMIC_RELEASE, __HIP_MEMORY_SCOPE_AGENT);
        } else {
            while (__hip_atomic_load(gen, __ATOMIC_ACQUIRE, __HIP_MEMORY_SCOPE_AGENT) == g)
                __builtin_amdgcn_s_sleep(8);
        }
        __threadfence();
    }
    __syncthreads();
}

__global__ __launch_bounds__(RT) void k_rest(
    const float* __restrict__ x,
    const float* __restrict__ h0,
    const float* __restrict__ W_ih,   const float* __restrict__ b_ih,
    const float* __restrict__ W_hh,   const float* __restrict__ b_hh,
    const float* __restrict__ W_halt, const float* __restrict__ b_halt,
    const float* __restrict__ hpart,  float* ws)
{
    int* wsI = (int*)ws;
    if (h0[0] >= THRESH) return;     // no steps ran at all

    const int tid = threadIdx.x, bid = blockIdx.x;
    const int wave = tid >> 6, lane = tid & 63;

    // ---- recompute step-0 halt decision from partials (uniform across blocks)
    {
        const float4* p4 = (const float4*)hpart;   // out[0..H) as H/4 float4
        float a = 0.f;
        #pragma unroll
        for (int j = 0; j < 4; ++j) {
            float4 v = p4[tid + (j << 8)];
            a += v.x + v.y + v.z + v.w;
        }
        a = wave_reduce(a);
        __shared__ float pr[4];
        if (lane == 0) pr[wave] = a;
        __syncthreads();
        float hd  = pr[0] + pr[1] + pr[2] + pr[3];
        float sg  = 1.f / (1.f + expf(-(hd + b_halt[0])));
        float acc0 = h0[0] + 2.f * sg;
        if (acc0 >= THRESH) {        // halted at step 0: common case
            if (bid == 0 && tid == 0) {
                wsI[4] = 1; wsI[5] = 0; wsI[6] = 0; ws[8] = acc0;
            }
            return;
        }
        if (bid == 0 && tid == 0) { wsI[4] = 0; }
        __syncthreads();
    }

    float* hdot = ws + 16;
    float* sb0  = ws + 32;
    float* sb1  = ws + 32 + H;

    __shared__ float xl[H];
    __shared__ float sl[H];
    if (tid == 0) xl[0] = 0.f;       // flag = 0 for all t >= 1
    for (int i = tid; i < H - 1; i += RT) xl[i + 1] = x[i];

    // recompute acc0 locally (cheap, uniform)
    float acc;
    {
        const float4* p4 = (const float4*)hpart;
        float a = 0.f;
        #pragma unroll
        for (int j = 0; j < 4; ++j) {
            float4 v = p4[tid + (j << 8)];
            a += v.x + v.y + v.z + v.w;
        }
        a = wave_reduce(a);
        __shared__ float pr2[4];
        if (lane == 0) pr2[wave] = a;
        __syncthreads();
        float hd = pr2[0] + pr2[1] + pr2[2] + pr2[3];
        acc = h0[0] + 2.f / (1.f + expf(-(hd + b_halt[0])));
    }
    int   ponder = 1;
    const float bh = b_halt[0];
    bool  halted = false;
    int   sel = 0;
    float last_acc = 0.f;

    for (int t = 1; t < NMAX; ++t) {
        const float* scur = (t & 1) ? sb0 : sb1;
        float*       snew = (t & 1) ? sb1 : sb0;

        __syncthreads();
        for (int i = tid; i < H / 4; i += RT)
            ((float4*)sl)[i] = ((const float4*)scur)[i];
        __syncthreads();

        for (int r = 0; r < 4; ++r) {
            const int row = bid * 16 + r * 4 + wave;
            const float4* wih = (const float4*)(W_ih + (size_t)row * H);
            const float4* whh = (const float4*)(W_hh + (size_t)row * H);
            float a0 = 0.f, a1 = 0.f;
            #pragma unroll 4
            for (int k = 0; k < 16; ++k) {
                const int idx = lane + (k << 6);
                float4 wa = wih[idx], wb = whh[idx];
                float4 va = ((const float4*)xl)[idx], vb = ((const float4*)sl)[idx];
                a0 += wa.x*va.x + wa.y*va.y + wa.z*va.z + wa.w*va.w;
                a1 += wb.x*vb.x + wb.y*vb.y + wb.z*vb.z + wb.w*vb.w;
            }
            float a = wave_reduce(a0 + a1);
            if (lane == 0) {
                float sv = tanhf(a + b_ih[row] + b_hh[row]);
                snew[row] = sv;
                atomicAdd(&hdot[t], W_halt[row] * sv);   // rare path: contention OK
            }
        }

        grid_barrier((int*)ws, (int*)ws + 1);

        float hd = ((volatile float*)hdot)[t];
        float sg = 1.f / (1.f + expf(-(hd + bh)));
        acc += 2.f * sg;
        if (acc >= THRESH) { halted = true; last_acc = acc; sel = (t & 1) ? 1 : 0; break; }
        ponder++;
    }

    if (bid == 0 && tid == 0) {
        wsI[4] = halted ? 1 : 0;
        wsI[5] = sel;
        wsI[6] = ponder;
        ws[8]  = last_acc;
    }
}

// ---------------- k_out: output matvec + epilogue ----------------
// 512 blocks x 256 thr; wave = 2 rows (rowA, rowA+2048); ping-pong nt batches.
__global__ __launch_bounds__(256, 4) void k_out(
    const float* __restrict__ s0,    const float* __restrict__ y0,
    const float* __restrict__ h0,
    const float* __restrict__ W_out, const float* __restrict__ b_out,
    const float* __restrict__ ws, float* __restrict__ out)
{
    const float h0v = h0[0];
    const int tid = threadIdx.x, bid = blockIdx.x;

    if (h0v >= THRESH) {             // binarize(h0)==1: pass-through
        const int i = bid * 256 + tid;
        if (i < H) { out[i] = y0[i]; out[H + i] = s0[i]; }
        if (i == 0) { out[2*H] = 0.f; out[2*H + 1] = h0v - 1.f; }
        return;
    }

    const int* wsI = (const int*)ws;
    if (!wsI[4]) {                   // never halted within NMAX steps
        const int i = bid * 256 + tid;
        if (i < H) { out[i] = 0.f; out[H + i] = 0.f; }
        if (i == 0) { out[2*H] = (float)wsI[6]; out[2*H + 1] = -1.f; }
        return;
    }

    const float* sfin = ws + 32 + (wsI[5] ? H : 0);
    const int wave = tid >> 6, lane = tid & 63;
    const int rowA = (bid << 2) + wave;        // 512 x 4 = 2048
    const int rowB = rowA + 2048;

    const nf4* wA4 = (const nf4*)(W_out + (size_t)rowA * H);
    const nf4* wB4 = (const nf4*)(W_out + (size_t)rowB * H);
    const float4* v4 = (const float4*)sfin;

    nf4 A[8], B[8];
    #pragma unroll
    for (int k = 0; k < 8; ++k)
        A[k] = __builtin_nontemporal_load(&wA4[lane + (k << 6)]);
    #pragma unroll
    for (int k = 0; k < 8; ++k)
        B[k] = __builtin_nontemporal_load(&wA4[lane + ((k + 8) << 6)]);

    float accA = 0.f, accB = 0.f;
    #pragma unroll
    for (int k = 0; k < 8; ++k) {
        float4 v = v4[lane + (k << 6)];
        accA += A[k].x*v.x + A[k].y*v.y + A[k].z*v.z + A[k].w*v.w;
    }
    #pragma unroll
    for (int k = 0; k < 8; ++k)
        A[k] = __builtin_nontemporal_load(&wB4[lane + (k << 6)]);
    #pragma unroll
    for (int k = 0; k < 8; ++k) {
        float4 v = v4[lane + ((k + 8) << 6)];
        accA += B[k].x*v.x + B[k].y*v.y + B[k].z*v.z + B[k].w*v.w;
    }
    #pragma unroll
    for (int k = 0; k < 8; ++k)
        B[k] = __builtin_nontemporal_load(&wB4[lane + ((k + 8) << 6)]);
    #pragma unroll
    for (int k = 0; k < 8; ++k) {
        float4 v = v4[lane + (k << 6)];
        accB += A[k].x*v.x + A[k].y*v.y + A[k].z*v.z + A[k].w*v.w;
    }
    #pragma unroll
    for (int k = 0; k < 8; ++k) {
        float4 v = v4[lane + ((k + 8) << 6)];
        accB += B[k].x*v.x + B[k].y*v.y + B[k].z*v.z + B[k].w*v.w;
    }

    float ra = wave_reduce(accA);
    float rb = wave_reduce(accB);
    if (lane == 0) {
        out[rowA]     = ra + b_out[rowA];
        out[rowB]     = rb + b_out[rowB];
        out[H + rowA] = sfin[rowA];
        out[H + rowB] = sfin[rowB];
        if (bid == 0 && wave == 0) {
            out[2*H]     = (float)wsI[6];
            out[2*H + 1] = ws[8] - 1.f;
        }
    }
}

extern "C" void kernel_launch(void* const* d_in, const int* in_sizes, int n_in,
                              void* d_out, int out_size, void* d_ws, size_t ws_size,
                              hipStream_t stream) {
    const float* x      = (const float*)d_in[0];
    const float* s0     = (const float*)d_in[1];
    const float* y0     = (const float*)d_in[2];
    const float* h0     = (const float*)d_in[3];
    const float* W_ih   = (const float*)d_in[4];
    const float* b_ih   = (const float*)d_in[5];
    const float* W_hh   = (const float*)d_in[6];
    const float* b_hh   = (const float*)d_in[7];
    const float* W_halt = (const float*)d_in[8];
    const float* b_halt = (const float*)d_in[9];
    const float* W_out  = (const float*)d_in[10];
    const float* b_out  = (const float*)d_in[11];
    float* out = (float*)d_out;
    float* ws  = (float*)d_ws;   // (32 + 2*4096)*4 B ≈ 33 KB used

    k_prep<<<dim3(16),   dim3(256), 0, stream>>>(x, ws, out);
    k_step0<<<dim3(1024), dim3(256), 0, stream>>>(
        s0, h0, W_ih, b_ih, W_hh, b_hh, W_halt, ws, out);
    k_rest<<<dim3(RG),   dim3(RT),  0, stream>>>(
        x, h0, W_ih, b_ih, W_hh, b_hh, W_halt, b_halt, out, ws);
    k_out<<<dim3(512),   dim3(256), 0, stream>>>(
        s0, y0, h0, W_out, b_out, ws, out);
}